// Round 3
// baseline (4479.367 us; speedup 1.0000x reference)
//
#include <hip/hip_runtime.h>
#include <hip/hip_bf16.h>
#include <hip/hip_cooperative_groups.h>
#include <stdint.h>

namespace cg = cooperative_groups;

// Autoregressive LSTM decode, B=4096, H=1024, A=128, 50 steps.
// Persistent cooperative kernel: 256 blocks x 512 threads, 1 grid.sync/step.
// gates = h @ (w_ih+w_hh)^T + bias (256^2-tile 8-phase, T1+T2+T3+T4+T5),
// cell state c lives in registers for all 50 steps, pred GEMM fused
// (direct-global MFMA, no LDS) and overlapped with next-step prologue staging.

#define B_SZ   4096
#define H_SZ   1024
#define A_SZ   128
#define NSTEP  50
#define NT     16      // K tiles of 64 (K = 1024)

using bf16 = __hip_bfloat16;
typedef __attribute__((ext_vector_type(8))) short bf16x8;
typedef __attribute__((ext_vector_type(4))) float f32x4;

__device__ __forceinline__ void gload_lds16(const void* g, void* l) {
    __builtin_amdgcn_global_load_lds(
        (const __attribute__((address_space(1))) unsigned int*)g,
        (__attribute__((address_space(3))) unsigned int*)l, 16, 0, 0);
}

#define FENCE() asm volatile("" ::: "memory")
#define BAR()   do { FENCE(); __builtin_amdgcn_s_barrier(); FENCE(); } while (0)
#define VMC6()  asm volatile("s_waitcnt vmcnt(6)" ::: "memory")
#define VMC0()  asm volatile("s_waitcnt vmcnt(0)" ::: "memory")
#define LGKM0() asm volatile("s_waitcnt lgkmcnt(0)" ::: "memory")

__device__ __forceinline__ float sigf(float x) {
    return 1.f / (1.f + __expf(-x));
}
__device__ __forceinline__ float tanh_(float x) {
    float e = __expf(-2.f * fabsf(x));
    float t = (1.f - e) / (1.f + e);
    return copysignf(t, x);
}

// ---------------- prep kernels ----------------

__global__ void prep_weights(const float4* __restrict__ wih,
                             const float4* __restrict__ whh,
                             bf16* __restrict__ Wc, bf16* __restrict__ Wi) {
    int i = blockIdx.x * 256 + threadIdx.x;
    float4 a = wih[i], b = whh[i];
    bf16 tc[4] = {__float2bfloat16(a.x + b.x), __float2bfloat16(a.y + b.y),
                  __float2bfloat16(a.z + b.z), __float2bfloat16(a.w + b.w)};
    bf16 ti[4] = {__float2bfloat16(a.x), __float2bfloat16(a.y),
                  __float2bfloat16(a.z), __float2bfloat16(a.w)};
    *(uint64_t*)(Wc + 4 * (size_t)i) = *(const uint64_t*)tc;
    *(uint64_t*)(Wi + 4 * (size_t)i) = *(const uint64_t*)ti;
}

__global__ void prep_cast(const float4* __restrict__ in, bf16* __restrict__ out) {
    int i = blockIdx.x * 256 + threadIdx.x;
    float4 a = in[i];
    bf16 t[4] = {__float2bfloat16(a.x), __float2bfloat16(a.y),
                 __float2bfloat16(a.z), __float2bfloat16(a.w)};
    *(uint64_t*)(out + 4 * (size_t)i) = *(const uint64_t*)t;
}

__global__ void prep_bias(const float* __restrict__ a, const float* __restrict__ b,
                          float* __restrict__ o) {
    int i = blockIdx.x * 256 + threadIdx.x;
    o[i] = a[i] + b[i];
}

// ---------------- persistent LSTM kernel ----------------

__global__ __launch_bounds__(512, 2)
void lstm_persist(const bf16* __restrict__ Wc, const bf16* __restrict__ Wi,
                  bf16* __restrict__ hA, bf16* __restrict__ hB,
                  const float* __restrict__ bias, const bf16* __restrict__ wp,
                  const float* __restrict__ bp, float* __restrict__ out) {
    cg::grid_group grid = cg::this_grid();
    __shared__ __align__(16) bf16 sm[65536];          // 128 KiB
    bf16* const lA0 = sm;
    bf16* const lA1 = sm + 16384;
    bf16* const lB0 = sm + 32768;
    bf16* const lB1 = sm + 49152;

    const int tid    = threadIdx.x;
    const int w      = tid >> 6;
    const int lane   = tid & 63;
    const int wr     = w >> 2;
    const int wc     = w & 3;
    const int lane15 = lane & 15;
    const int lhi    = lane >> 4;

    const int bid     = blockIdx.x;
    const int logical = (bid & 7) * 32 + (bid >> 3);   // bijective XCD swizzle
    const int bm0     = (logical >> 4) * 256;
    const int j0      = (logical & 15) * 64;

    const int scolb = ((tid & 7) * 16) ^ (((tid >> 3) & 7) << 4);
    const size_t offA = (size_t)(bm0 + (tid >> 3)) * 2048 + scolb;
    const size_t offB = (size_t)(j0  + (tid >> 3)) * 2048 + scolb;

    const int cs0 = ((     lhi * 16) ^ ((lane & 7) << 4)) >> 1;
    const int cs1 = ((64 + lhi * 16) ^ ((lane & 7) << 4)) >> 1;
    const int rA  = (wr * 128 + lane15) * 64;
    const int rB  = (wc * 16  + lane15) * 64;

    // hoisted per-session constants
    const int jc = j0 + wc * 16 + lane15;
    const float bi  = bias[jc];
    const float bff = bias[H_SZ + jc];
    const float bg  = bias[2 * H_SZ + jc];
    const float bo  = bias[3 * H_SZ + jc];
    const float bpv = bp[w * 16 + lane15];
    const int pr0 = logical * 16;                      // pred rows for this block

    float creg[8][4];                                   // cell state, registers
#pragma unroll
    for (int m = 0; m < 8; ++m)
#pragma unroll
        for (int r = 0; r < 4; ++r) creg[m][r] = 0.f;

    const char* gA = (const char*)hA + offA;            // step 0: x0
    const char* gB = (const char*)Wi + offB;            // step 0: w_ih only

    auto SGA = [&](int t, int h) {
        bf16* dst = ((t & 1) ? lA1 : lA0) + h * 8192 + w * 512;
        const char* g = gA + (size_t)(h * 128) * 2048 + (size_t)t * 128;
        gload_lds16(g, dst);
        gload_lds16(g + (size_t)64 * 2048, dst + 4096);
    };
    auto SGB = [&](int t, int h) {
        bf16* dst = ((t & 1) ? lB1 : lB0) + h * 8192 + w * 512;
        const char* g = gB + (size_t)(h * 2) * 2097152 + (size_t)t * 128;
        gload_lds16(g, dst);
        gload_lds16(g + 2097152, dst + 4096);
    };

    // prologue for step 0
    SGB(0, 0); SGB(0, 1); SGA(0, 0); SGA(0, 1);
    SGB(1, 0); SGB(1, 1); SGA(1, 0);

    const f32x4 z = {0.f, 0.f, 0.f, 0.f};

    for (int s = 0; s < NSTEP; ++s) {
        bf16* hnew = (s & 1) ? hA : hB;

        VMC6();            // tile 0 landed (prologue is oldest in vmcnt order)
        BAR();

        f32x4 acc[8][4];
#pragma unroll
        for (int m = 0; m < 8; ++m)
#pragma unroll
            for (int n = 0; n < 4; ++n) acc[m][n] = z;

        for (int t = 0; t < NT; ++t) {
            const bf16* Ad = (t & 1) ? lA1 : lA0;
            const bf16* Bd = (t & 1) ? lB1 : lB0;
            bf16x8 av[4][2], bv[4][2];

            // phase 0: m0-3 x n0-1; stage A1(t+1)
#pragma unroll
            for (int m = 0; m < 4; ++m) {
                av[m][0] = *(const bf16x8*)(Ad + rA + m * 1024 + cs0);
                av[m][1] = *(const bf16x8*)(Ad + rA + m * 1024 + cs1);
            }
#pragma unroll
            for (int n = 0; n < 2; ++n) {
                bv[n][0] = *(const bf16x8*)(Bd + rB + n * 4096 + cs0);
                bv[n][1] = *(const bf16x8*)(Bd + rB + n * 4096 + cs1);
            }
            if (t + 1 < NT) SGA(t + 1, 1);
            BAR(); LGKM0();
            __builtin_amdgcn_s_setprio(1);
#pragma unroll
            for (int n = 0; n < 2; ++n)
#pragma unroll
                for (int m = 0; m < 4; ++m) {
                    acc[m][n] = __builtin_amdgcn_mfma_f32_16x16x32_bf16(av[m][0], bv[n][0], acc[m][n], 0, 0, 0);
                    acc[m][n] = __builtin_amdgcn_mfma_f32_16x16x32_bf16(av[m][1], bv[n][1], acc[m][n], 0, 0, 0);
                }
            __builtin_amdgcn_s_setprio(0);
            BAR();

            // phase 1: m0-3 x n2-3; stage B0(t+2)
#pragma unroll
            for (int n = 2; n < 4; ++n) {
                bv[n][0] = *(const bf16x8*)(Bd + rB + n * 4096 + cs0);
                bv[n][1] = *(const bf16x8*)(Bd + rB + n * 4096 + cs1);
            }
            if (t + 2 < NT) SGB(t + 2, 0);
            BAR(); LGKM0();
            __builtin_amdgcn_s_setprio(1);
#pragma unroll
            for (int n = 2; n < 4; ++n)
#pragma unroll
                for (int m = 0; m < 4; ++m) {
                    acc[m][n] = __builtin_amdgcn_mfma_f32_16x16x32_bf16(av[m][0], bv[n][0], acc[m][n], 0, 0, 0);
                    acc[m][n] = __builtin_amdgcn_mfma_f32_16x16x32_bf16(av[m][1], bv[n][1], acc[m][n], 0, 0, 0);
                }
            __builtin_amdgcn_s_setprio(0);
            BAR();

            // phase 2: m4-7 x n0-1; stage B1(t+2)
#pragma unroll
            for (int m = 0; m < 4; ++m) {
                av[m][0] = *(const bf16x8*)(Ad + rA + (m + 4) * 1024 + cs0);
                av[m][1] = *(const bf16x8*)(Ad + rA + (m + 4) * 1024 + cs1);
            }
            if (t + 2 < NT) SGB(t + 2, 1);
            BAR(); LGKM0();
            __builtin_amdgcn_s_setprio(1);
#pragma unroll
            for (int n = 0; n < 2; ++n)
#pragma unroll
                for (int m = 0; m < 4; ++m) {
                    acc[m + 4][n] = __builtin_amdgcn_mfma_f32_16x16x32_bf16(av[m][0], bv[n][0], acc[m + 4][n], 0, 0, 0);
                    acc[m + 4][n] = __builtin_amdgcn_mfma_f32_16x16x32_bf16(av[m][1], bv[n][1], acc[m + 4][n], 0, 0, 0);
                }
            __builtin_amdgcn_s_setprio(0);
            BAR();

            // phase 3: m4-7 x n2-3; stage A0(t+2)
            if (t + 2 < NT) SGA(t + 2, 0);
            BAR(); LGKM0();
            __builtin_amdgcn_s_setprio(1);
#pragma unroll
            for (int n = 2; n < 4; ++n)
#pragma unroll
                for (int m = 0; m < 4; ++m) {
                    acc[m + 4][n] = __builtin_amdgcn_mfma_f32_16x16x32_bf16(av[m][0], bv[n][0], acc[m + 4][n], 0, 0, 0);
                    acc[m + 4][n] = __builtin_amdgcn_mfma_f32_16x16x32_bf16(av[m][1], bv[n][1], acc[m + 4][n], 0, 0, 0);
                }
            __builtin_amdgcn_s_setprio(0);
            if (t < NT - 1) {
                if (t == NT - 2) { VMC0(); } else { VMC6(); }
            }
            BAR();
        }

        // ---- fused LSTM cell epilogue (c in registers, no memory traffic)
#pragma unroll
        for (int m = 0; m < 8; ++m) {
#pragma unroll
            for (int r = 0; r < 4; ++r) {
                int row = bm0 + wr * 128 + m * 16 + lhi * 4 + r;
                float iv = acc[m][0][r] + bi;
                float fv = acc[m][1][r] + bff;
                float gv = acc[m][2][r] + bg;
                float ov = acc[m][3][r] + bo;
                float cn = sigf(fv) * creg[m][r] + sigf(iv) * tanh_(gv);
                float hn = sigf(ov) * tanh_(cn);
                creg[m][r] = cn;
                hnew[(size_t)row * H_SZ + jc] = __float2bfloat16(hn);
            }
        }

        grid.sync();

        // ---- issue next step's prologue (hidden under pred phase)
        if (s + 1 < NSTEP) {
            gA = (const char*)hnew + offA;
            gB = (const char*)Wc + offB;
            SGB(0, 0); SGB(0, 1); SGA(0, 0); SGA(0, 1);
            SGB(1, 0); SGB(1, 1); SGA(1, 0);
        }

        // ---- pred GEMM: out[s] = hnew @ wp^T + bp (direct-global, no LDS)
        const bf16* hp  = hnew + (size_t)(pr0 + lane15) * H_SZ + lhi * 8;
        const bf16* wpp = wp   + (size_t)(w * 16 + lane15) * H_SZ + lhi * 8;
        f32x4 pacc = z;
#pragma unroll 4
        for (int ks = 0; ks < 32; ++ks) {
            bf16x8 a = *(const bf16x8*)(hp + ks * 32);
            bf16x8 b = *(const bf16x8*)(wpp + ks * 32);
            pacc = __builtin_amdgcn_mfma_f32_16x16x32_bf16(a, b, pacc, 0, 0, 0);
        }
        float* op = out + (size_t)s * (B_SZ * A_SZ)
                  + (size_t)(pr0 + lhi * 4) * A_SZ + w * 16 + lane15;
#pragma unroll
        for (int r = 0; r < 4; ++r) op[r * A_SZ] = pacc[r] + bpv;
    }
}

// ---------------- launcher ----------------

extern "C" void kernel_launch(void* const* d_in, const int* in_sizes, int n_in,
                              void* d_out, int out_size, void* d_ws, size_t ws_size,
                              hipStream_t stream) {
    const float* enc   = (const float*)d_in[0];
    const float* wih   = (const float*)d_in[1];
    const float* whh   = (const float*)d_in[2];
    const float* bih   = (const float*)d_in[3];
    const float* bhh   = (const float*)d_in[4];
    const float* wpred = (const float*)d_in[5];
    const float* bpred = (const float*)d_in[6];
    float* out = (float*)d_out;

    char* ws = (char*)d_ws;
    const size_t WH = (size_t)4 * H_SZ * H_SZ;
    const size_t BH = (size_t)B_SZ * H_SZ;
    bf16*  Wc   = (bf16*)ws;                 ws += WH * 2;
    bf16*  Wi   = (bf16*)ws;                 ws += WH * 2;
    bf16*  h0   = (bf16*)ws;                 ws += BH * 2;
    bf16*  h1   = (bf16*)ws;                 ws += BH * 2;
    bf16*  wp   = (bf16*)ws;                 ws += (size_t)A_SZ * H_SZ * 2;
    float* bias = (float*)ws;                ws += 4 * H_SZ * 4;

    prep_weights<<<4096, 256, 0, stream>>>((const float4*)wih, (const float4*)whh, Wc, Wi);
    prep_cast<<<128, 256, 0, stream>>>((const float4*)wpred, wp);
    prep_bias<<<16, 256, 0, stream>>>(bih, bhh, bias);
    prep_cast<<<4096, 256, 0, stream>>>((const float4*)enc, h0);

    void* args[] = {(void*)&Wc, (void*)&Wi, (void*)&h0, (void*)&h1,
                    (void*)&bias, (void*)&wp, (void*)&bpred, (void*)&out};
    hipLaunchCooperativeKernel((const void*)lstm_persist, dim3(256), dim3(512),
                               args, 0, stream);
}

// Round 4
// 2819.171 us; speedup vs baseline: 1.5889x; 1.5889x over previous
//
#include <hip/hip_runtime.h>
#include <hip/hip_bf16.h>
#include <stdint.h>

// Autoregressive LSTM decode, B=4096, H=1024, A=128, 50 steps.
// steps>=1: x==h  =>  gates = h @ (w_ih+w_hh)^T + bias.
// Gates GEMM: 256^2-tile 8-phase schedule (T1+T2+T3+T4+T5), fused LSTM cell.
// Pred GEMM for step s-1 is fused into gates launch s (it reads only h(s),
// the gates input), overlapped with the prologue's global_load_lds staging.

#define B_SZ   4096
#define H_SZ   1024
#define A_SZ   128
#define NSTEP  50
#define NT     16      // K tiles of 64 (K = 1024)

using bf16 = __hip_bfloat16;
typedef __attribute__((ext_vector_type(8))) short bf16x8;   // 8 bf16 = 4 VGPR
typedef __attribute__((ext_vector_type(4))) float f32x4;    // MFMA C/D frag

__device__ __forceinline__ void gload_lds16(const void* g, void* l) {
    __builtin_amdgcn_global_load_lds(
        (const __attribute__((address_space(1))) unsigned int*)g,
        (__attribute__((address_space(3))) unsigned int*)l, 16, 0, 0);
}

#define FENCE() asm volatile("" ::: "memory")
#define BAR()   do { FENCE(); __builtin_amdgcn_s_barrier(); FENCE(); } while (0)
#define VMC6()  asm volatile("s_waitcnt vmcnt(6)" ::: "memory")
#define VMC0()  asm volatile("s_waitcnt vmcnt(0)" ::: "memory")
#define LGKM0() asm volatile("s_waitcnt lgkmcnt(0)" ::: "memory")

__device__ __forceinline__ float sigf(float x) {
    return 1.f / (1.f + __expf(-x));
}
__device__ __forceinline__ float tanh_(float x) {
    float e = __expf(-2.f * fabsf(x));
    float t = (1.f - e) / (1.f + e);
    return copysignf(t, x);
}

// ---------------- prep kernels (run once per launch) ----------------

__global__ void prep_weights(const float4* __restrict__ wih,
                             const float4* __restrict__ whh,
                             bf16* __restrict__ Wc, bf16* __restrict__ Wi) {
    int i = blockIdx.x * 256 + threadIdx.x;
    float4 a = wih[i], b = whh[i];
    bf16 tc[4] = {__float2bfloat16(a.x + b.x), __float2bfloat16(a.y + b.y),
                  __float2bfloat16(a.z + b.z), __float2bfloat16(a.w + b.w)};
    bf16 ti[4] = {__float2bfloat16(a.x), __float2bfloat16(a.y),
                  __float2bfloat16(a.z), __float2bfloat16(a.w)};
    *(uint64_t*)(Wc + 4 * (size_t)i) = *(const uint64_t*)tc;
    *(uint64_t*)(Wi + 4 * (size_t)i) = *(const uint64_t*)ti;
}

__global__ void prep_cast(const float4* __restrict__ in, bf16* __restrict__ out) {
    int i = blockIdx.x * 256 + threadIdx.x;
    float4 a = in[i];
    bf16 t[4] = {__float2bfloat16(a.x), __float2bfloat16(a.y),
                 __float2bfloat16(a.z), __float2bfloat16(a.w)};
    *(uint64_t*)(out + 4 * (size_t)i) = *(const uint64_t*)t;
}

__global__ void prep_bias(const float* __restrict__ a, const float* __restrict__ b,
                          float* __restrict__ o) {
    int i = blockIdx.x * 256 + threadIdx.x;
    o[i] = a[i] + b[i];
}

// ---------------- fused gates GEMM + LSTM cell + prev-step pred ----------------
// grid: 256 blocks (1/CU, XCD-swizzled). Block: 256 batch rows x (4 gates x 64 j).
// 8 waves 2Mx4N; acc[8 m][4 gates]. LDS: A/B double-buffered, 128 KiB, swizzled.
// pout != null: also compute pout = hin @ wp^T + bp for this block's 16 rows,
// placed under the prologue staging latency (pred loads are younger than the
// prologue gload_lds, so VMC6 accounting is unchanged).

__global__ __launch_bounds__(512, 2)
void lstm_gates(const bf16* __restrict__ hin, const bf16* __restrict__ W,
                const float* __restrict__ bias, float* __restrict__ c,
                bf16* __restrict__ hout, int step0,
                const bf16* __restrict__ wp, const float* __restrict__ bp,
                float* __restrict__ pout) {
    __shared__ __align__(16) bf16 sm[65536];          // 128 KiB
    bf16* const lA0 = sm;
    bf16* const lA1 = sm + 16384;
    bf16* const lB0 = sm + 32768;
    bf16* const lB1 = sm + 49152;

    const int tid    = threadIdx.x;
    const int w      = tid >> 6;
    const int lane   = tid & 63;
    const int wr     = w >> 2;
    const int wc     = w & 3;
    const int lane15 = lane & 15;
    const int lhi    = lane >> 4;

    const int bid     = blockIdx.x;
    const int logical = (bid & 7) * 32 + (bid >> 3);   // bijective XCD swizzle
    const int bm0     = (logical >> 4) * 256;
    const int j0      = (logical & 15) * 64;

    const int scolb = ((tid & 7) * 16) ^ (((tid >> 3) & 7) << 4);
    const char* baseA = (const char*)hin + (size_t)(bm0 + (tid >> 3)) * 2048 + scolb;
    const char* baseB = (const char*)W   + (size_t)(j0  + (tid >> 3)) * 2048 + scolb;

    const int cs0 = ((     lhi * 16) ^ ((lane & 7) << 4)) >> 1;
    const int cs1 = ((64 + lhi * 16) ^ ((lane & 7) << 4)) >> 1;
    const int rA  = (wr * 128 + lane15) * 64;
    const int rB  = (wc * 16  + lane15) * 64;

    f32x4 acc[8][4];
    const f32x4 z = {0.f, 0.f, 0.f, 0.f};
#pragma unroll
    for (int m = 0; m < 8; ++m)
#pragma unroll
        for (int n = 0; n < 4; ++n) acc[m][n] = z;

    auto SGA = [&](int t, int h) {
        bf16* dst = ((t & 1) ? lA1 : lA0) + h * 8192 + w * 512;
        const char* g = baseA + (size_t)(h * 128) * 2048 + (size_t)t * 128;
        gload_lds16(g, dst);
        gload_lds16(g + (size_t)64 * 2048, dst + 4096);
    };
    auto SGB = [&](int t, int h) {
        bf16* dst = ((t & 1) ? lB1 : lB0) + h * 8192 + w * 512;
        const char* g = baseB + (size_t)(h * 2) * 2097152 + (size_t)t * 128;
        gload_lds16(g, dst);
        gload_lds16(g + 2097152, dst + 4096);
    };

    // prologue: 7 half-tile stages (14 gload_lds, oldest in vmcnt order)
    SGB(0, 0); SGB(0, 1); SGA(0, 0); SGA(0, 1);
    SGB(1, 0); SGB(1, 1); SGA(1, 0);

    // ---- fused pred for the PREVIOUS step: pout = hin @ wp^T + bp.
    // Runs while prologue stages land; its loads are younger than the
    // prologue's, so VMC6 below still guarantees tile 0 is resident.
    if (pout) {
        const int pr0 = logical * 16;
        const bf16* hp  = hin + (size_t)(pr0 + lane15) * H_SZ + lhi * 8;
        const bf16* wpp = wp  + (size_t)(w * 16 + lane15) * H_SZ + lhi * 8;
        f32x4 pacc = z;
#pragma unroll 4
        for (int ks = 0; ks < 32; ++ks) {
            bf16x8 a = *(const bf16x8*)(hp + ks * 32);
            bf16x8 b = *(const bf16x8*)(wpp + ks * 32);
            pacc = __builtin_amdgcn_mfma_f32_16x16x32_bf16(a, b, pacc, 0, 0, 0);
        }
        const float bpv = bp[w * 16 + lane15];
        float* op = pout + (size_t)(pr0 + lhi * 4) * A_SZ + w * 16 + lane15;
#pragma unroll
        for (int r = 0; r < 4; ++r) op[r * A_SZ] = pacc[r] + bpv;
    }

    VMC6();
    BAR();

    for (int t = 0; t < NT; ++t) {
        const bf16* Ad = (t & 1) ? lA1 : lA0;
        const bf16* Bd = (t & 1) ? lB1 : lB0;
        bf16x8 av[4][2], bv[4][2];

        // phase 0: m0-3 x n0-1; stage A1(t+1)
#pragma unroll
        for (int m = 0; m < 4; ++m) {
            av[m][0] = *(const bf16x8*)(Ad + rA + m * 1024 + cs0);
            av[m][1] = *(const bf16x8*)(Ad + rA + m * 1024 + cs1);
        }
#pragma unroll
        for (int n = 0; n < 2; ++n) {
            bv[n][0] = *(const bf16x8*)(Bd + rB + n * 4096 + cs0);
            bv[n][1] = *(const bf16x8*)(Bd + rB + n * 4096 + cs1);
        }
        if (t + 1 < NT) SGA(t + 1, 1);
        BAR(); LGKM0();
        __builtin_amdgcn_s_setprio(1);
#pragma unroll
        for (int n = 0; n < 2; ++n)
#pragma unroll
            for (int m = 0; m < 4; ++m) {
                acc[m][n] = __builtin_amdgcn_mfma_f32_16x16x32_bf16(av[m][0], bv[n][0], acc[m][n], 0, 0, 0);
                acc[m][n] = __builtin_amdgcn_mfma_f32_16x16x32_bf16(av[m][1], bv[n][1], acc[m][n], 0, 0, 0);
            }
        __builtin_amdgcn_s_setprio(0);
        BAR();

        // phase 1: m0-3 x n2-3; stage B0(t+2)
#pragma unroll
        for (int n = 2; n < 4; ++n) {
            bv[n][0] = *(const bf16x8*)(Bd + rB + n * 4096 + cs0);
            bv[n][1] = *(const bf16x8*)(Bd + rB + n * 4096 + cs1);
        }
        if (t + 2 < NT) SGB(t + 2, 0);
        BAR(); LGKM0();
        __builtin_amdgcn_s_setprio(1);
#pragma unroll
        for (int n = 2; n < 4; ++n)
#pragma unroll
            for (int m = 0; m < 4; ++m) {
                acc[m][n] = __builtin_amdgcn_mfma_f32_16x16x32_bf16(av[m][0], bv[n][0], acc[m][n], 0, 0, 0);
                acc[m][n] = __builtin_amdgcn_mfma_f32_16x16x32_bf16(av[m][1], bv[n][1], acc[m][n], 0, 0, 0);
            }
        __builtin_amdgcn_s_setprio(0);
        BAR();

        // phase 2: m4-7 x n0-1; stage B1(t+2)
#pragma unroll
        for (int m = 0; m < 4; ++m) {
            av[m][0] = *(const bf16x8*)(Ad + rA + (m + 4) * 1024 + cs0);
            av[m][1] = *(const bf16x8*)(Ad + rA + (m + 4) * 1024 + cs1);
        }
        if (t + 2 < NT) SGB(t + 2, 1);
        BAR(); LGKM0();
        __builtin_amdgcn_s_setprio(1);
#pragma unroll
        for (int n = 0; n < 2; ++n)
#pragma unroll
            for (int m = 0; m < 4; ++m) {
                acc[m + 4][n] = __builtin_amdgcn_mfma_f32_16x16x32_bf16(av[m][0], bv[n][0], acc[m + 4][n], 0, 0, 0);
                acc[m + 4][n] = __builtin_amdgcn_mfma_f32_16x16x32_bf16(av[m][1], bv[n][1], acc[m + 4][n], 0, 0, 0);
            }
        __builtin_amdgcn_s_setprio(0);
        BAR();

        // phase 3: m4-7 x n2-3; stage A0(t+2)
        if (t + 2 < NT) SGA(t + 2, 0);
        BAR(); LGKM0();
        __builtin_amdgcn_s_setprio(1);
#pragma unroll
        for (int n = 2; n < 4; ++n)
#pragma unroll
            for (int m = 0; m < 4; ++m) {
                acc[m + 4][n] = __builtin_amdgcn_mfma_f32_16x16x32_bf16(av[m][0], bv[n][0], acc[m + 4][n], 0, 0, 0);
                acc[m + 4][n] = __builtin_amdgcn_mfma_f32_16x16x32_bf16(av[m][1], bv[n][1], acc[m + 4][n], 0, 0, 0);
            }
        __builtin_amdgcn_s_setprio(0);
        if (t < NT - 1) {
            if (t == NT - 2) { VMC0(); } else { VMC6(); }
        }
        BAR();
    }

    // ---- fused LSTM cell epilogue (i/f/g/o lane-local: n-frag == gate)
    const int jc = j0 + wc * 16 + lane15;
    const float bi  = bias[jc];
    const float bff = bias[H_SZ + jc];
    const float bg  = bias[2 * H_SZ + jc];
    const float bo  = bias[3 * H_SZ + jc];
#pragma unroll
    for (int m = 0; m < 8; ++m) {
#pragma unroll
        for (int r = 0; r < 4; ++r) {
            int row = bm0 + wr * 128 + m * 16 + lhi * 4 + r;
            size_t idx = (size_t)row * H_SZ + jc;
            float iv = acc[m][0][r] + bi;
            float fv = acc[m][1][r] + bff;
            float gv = acc[m][2][r] + bg;
            float ov = acc[m][3][r] + bo;
            float cp = step0 ? 0.f : c[idx];
            float cn = sigf(fv) * cp + sigf(iv) * tanh_(gv);
            float hn = sigf(ov) * tanh_(cn);
            c[idx] = cn;
            hout[idx] = __float2bfloat16(hn);
        }
    }
}

// ---------------- standalone pred (final step only) ----------------
// grid: B/16 = 256 blocks. Block: 16 rows x 128 cols, 4 waves.

__global__ __launch_bounds__(256)
void pred_kernel(const bf16* __restrict__ h, const bf16* __restrict__ wp,
                 const float* __restrict__ bp, float* __restrict__ out) {
    __shared__ __align__(16) bf16 lH[16 * 64];      // 2 KB
    __shared__ __align__(16) bf16 lP[128 * 64];     // 16 KB

    const int tid  = threadIdx.x;
    const int w    = tid >> 6;
    const int lane = tid & 63;
    const int bm0  = blockIdx.x * 16;

    const int scolb = ((tid & 7) * 16) ^ (((tid >> 3) & 7) << 4);
    const int cs0 = ((      (lane >> 4) * 16) ^ ((lane & 7) << 4)) >> 1;
    const int cs1 = ((64 + (lane >> 4) * 16) ^ ((lane & 7) << 4)) >> 1;

    f32x4 acc[2];
    const f32x4 z = {0.f, 0.f, 0.f, 0.f};
    acc[0] = z; acc[1] = z;

    const char* hb = (const char*)h  + (size_t)(bm0 + (tid >> 3)) * 2048 + scolb;
    const char* pb = (const char*)wp + (size_t)(tid >> 3) * 2048 + scolb;

    for (int t = 0; t < NT; ++t) {
        __syncthreads();
        if (tid < 128)
            gload_lds16(hb + (size_t)t * 128, lH + w * 512);
#pragma unroll
        for (int q = 0; q < 4; ++q)
            gload_lds16(pb + (size_t)(q * 32) * 2048 + (size_t)t * 128,
                        lP + (q * 4 + w) * 512);
        __syncthreads();

        bf16x8 a0 = *(const bf16x8*)(lH + (lane & 15) * 64 + cs0);
        bf16x8 a1 = *(const bf16x8*)(lH + (lane & 15) * 64 + cs1);
#pragma unroll
        for (int n = 0; n < 2; ++n) {
            int rowb = (w * 32 + n * 16 + (lane & 15)) * 64;
            bf16x8 b0 = *(const bf16x8*)(lP + rowb + cs0);
            bf16x8 b1 = *(const bf16x8*)(lP + rowb + cs1);
            acc[n] = __builtin_amdgcn_mfma_f32_16x16x32_bf16(a0, b0, acc[n], 0, 0, 0);
            acc[n] = __builtin_amdgcn_mfma_f32_16x16x32_bf16(a1, b1, acc[n], 0, 0, 0);
        }
    }

#pragma unroll
    for (int n = 0; n < 2; ++n)
#pragma unroll
        for (int r = 0; r < 4; ++r) {
            int row = bm0 + (lane >> 4) * 4 + r;
            int col = w * 32 + n * 16 + (lane & 15);
            out[(size_t)row * A_SZ + col] = acc[n][r] + bp[col];
        }
}

// ---------------- launcher ----------------

extern "C" void kernel_launch(void* const* d_in, const int* in_sizes, int n_in,
                              void* d_out, int out_size, void* d_ws, size_t ws_size,
                              hipStream_t stream) {
    const float* enc   = (const float*)d_in[0];
    const float* wih   = (const float*)d_in[1];
    const float* whh   = (const float*)d_in[2];
    const float* bih   = (const float*)d_in[3];
    const float* bhh   = (const float*)d_in[4];
    const float* wpred = (const float*)d_in[5];
    const float* bpred = (const float*)d_in[6];
    float* out = (float*)d_out;

    char* ws = (char*)d_ws;
    const size_t WH = (size_t)4 * H_SZ * H_SZ;
    const size_t BH = (size_t)B_SZ * H_SZ;
    bf16*  Wc   = (bf16*)ws;                 ws += WH * 2;
    bf16*  Wi   = (bf16*)ws;                 ws += WH * 2;
    bf16*  h0   = (bf16*)ws;                 ws += BH * 2;
    bf16*  h1   = (bf16*)ws;                 ws += BH * 2;
    float* cbuf = (float*)ws;                ws += BH * 4;
    bf16*  wp   = (bf16*)ws;                 ws += (size_t)A_SZ * H_SZ * 2;
    float* bias = (float*)ws;                ws += 4 * H_SZ * 4;

    prep_weights<<<4096, 256, 0, stream>>>((const float4*)wih, (const float4*)whh, Wc, Wi);
    prep_cast<<<128, 256, 0, stream>>>((const float4*)wpred, wp);
    prep_bias<<<16, 256, 0, stream>>>(bih, bhh, bias);
    prep_cast<<<4096, 256, 0, stream>>>((const float4*)enc, h0);

    bf16* hbuf[2] = {h0, h1};
    for (int s = 0; s < NSTEP; ++s) {
        const bf16* hin = hbuf[s & 1];
        bf16* hout      = hbuf[(s + 1) & 1];
        float* pout = (s == 0) ? nullptr : out + (size_t)(s - 1) * (B_SZ * A_SZ);
        lstm_gates<<<256, 512, 0, stream>>>(
            hin, (s == 0) ? Wi : Wc, bias, cbuf, hout, s == 0 ? 1 : 0,
            wp, bpred, pout);
    }
    // out[49] = h(50) @ wp^T + bp;  h(50) lives in hbuf[0] (step 49 wrote it)
    pred_kernel<<<256, 256, 0, stream>>>(
        hbuf[0], wp, bpred, out + (size_t)(NSTEP - 1) * (B_SZ * A_SZ));
}